// Round 1
// baseline (193.319 us; speedup 1.0000x reference)
//
#include <hip/hip_runtime.h>

// Problem constants (fixed by setup_inputs)
constexpr int H_  = 32;
constexpr int N_  = 256;
constexpr int BS_ = 32;
constexpr int W_  = 128;
constexpr int T_  = 4096;
constexpr int D_  = 128;
constexpr int NQ_ = 8192;          // N_*BS_
constexpr float SCALE_ = 0.08838834764831845f;  // 1/sqrt(128)
constexpr float L2E_   = 1.4426950408889634f;

typedef __attribute__((ext_vector_type(4))) float f4;
typedef __attribute__((ext_vector_type(4))) short s4;
typedef __attribute__((ext_vector_type(8))) short s8;
typedef __attribute__((ext_vector_type(4))) float fx4;

__device__ __forceinline__ short bfrne(float f) {   // fp32 -> bf16 bits, RNE
  unsigned u = __float_as_uint(f);
  u += 0x7fffu + ((u >> 16) & 1u);
  return (short)(u >> 16);
}
__device__ __forceinline__ float hipart(float f) {  // truncated-bf16 part as fp32
  return __uint_as_float(__float_as_uint(f) & 0xffff0000u);
}

__global__ __launch_bounds__(128)
void mtp_attn_kernel(const float* __restrict__ q,
                     const float* __restrict__ k_ctx,
                     const float* __restrict__ v_ctx,
                     const float* __restrict__ k_draft,
                     const float* __restrict__ v_draft,
                     const int* __restrict__ anchor,
                     const int* __restrict__ keepm,
                     float* __restrict__ out)
{
  // XCD-chunked swizzle: 8192 % 8 == 0 -> bijective; consecutive n share window rows in L2
  int u = blockIdx.x;
  u = (u & 7) * 1024 + (u >> 3);
  const int h = u >> 8;
  const int n = u & 255;

  const int tu   = threadIdx.x;  // 0..127, one unit per block
  const int lane = tu & 63;
  const int wu   = tu >> 6;      // wave id == M-tile (queries wu*16..+15)
  const int l15  = lane & 15;
  const int g    = lane >> 4;    // 0..3

  const int A  = anchor[n];
  const int kp = keepm[n];

  // LDS: phase1 K-chunk bf16 [32][136] (8704B) / phase2 V^T bf16 [128][36] (9216B) share;
  // P buffer bf16 [32][168] (10752B). Total 19968B -> up to 8 blocks/CU.
  __shared__ __align__(16) unsigned char smem_[19968];
  short* kb = (short*)smem_;
  short* vT = (short*)smem_;
  short* pb = (short*)(smem_ + 9216);

  // ---- Q fragments, hi/lo split, kept in registers ----
  // A-frag layout: m = l&15, k = (l>>4)*4 + (j&3) + 16*(j>>2) + 32*ks
  const float* qrow = q + ((size_t)h * NQ_ + (size_t)n * BS_ + wu * 16 + l15) * D_;
  s8 qh[4], ql[4];
#pragma unroll
  for (int ks = 0; ks < 4; ++ks) {
    f4 f0 = *reinterpret_cast<const f4*>(qrow + ks * 32 + g * 4);
    f4 f1 = *reinterpret_cast<const f4*>(qrow + ks * 32 + 16 + g * 4);
#pragma unroll
    for (int j = 0; j < 4; ++j) {
      float a = f0[j], b = f1[j];
      qh[ks][j]     = (short)(__float_as_uint(a) >> 16);
      qh[ks][j + 4] = (short)(__float_as_uint(b) >> 16);
      ql[ks][j]     = bfrne(a - hipart(a));
      ql[ks][j + 4] = bfrne(b - hipart(b));
    }
  }

  fx4 S[10];
#pragma unroll
  for (int t = 0; t < 10; ++t) S[t] = {0.f, 0.f, 0.f, 0.f};

  const int rb = tu >> 5;   // 0..3
  const int c4 = tu & 31;   // float4 column

  // ---- Phase 1: S = Q K^T (chunks of 32 keys) ----
#pragma unroll
  for (int c = 0; c < 5; ++c) {
    __syncthreads();
#pragma unroll
    for (int p = 0; p < 8; ++p) {
      int row = p * 4 + rb;
      int key = c * 32 + row;
      const float* src;
      if (key < W_) {
        int idx = A - W_ + key; idx = idx < 0 ? 0 : idx;  // masked later
        src = k_ctx + ((size_t)h * T_ + idx) * D_;
      } else {
        src = k_draft + ((size_t)h * NQ_ + (size_t)n * BS_ + (key - W_)) * D_;
      }
      f4 v = reinterpret_cast<const f4*>(src)[c4];
      s4 w = { bfrne(v[0]), bfrne(v[1]), bfrne(v[2]), bfrne(v[3]) };
      *reinterpret_cast<s4*>(kb + row * 136 + c4 * 4) = w;
    }
    __syncthreads();
#pragma unroll
    for (int t2 = 0; t2 < 2; ++t2) {
      const short* kpr = kb + (t2 * 16 + l15) * 136 + g * 4;
#pragma unroll
      for (int ks = 0; ks < 4; ++ks) {
        s4 b0 = *reinterpret_cast<const s4*>(kpr + ks * 32);
        s4 b1 = *reinterpret_cast<const s4*>(kpr + ks * 32 + 16);
        s8 kf = { b0[0], b0[1], b0[2], b0[3], b1[0], b1[1], b1[2], b1[3] };
        fx4 acc = S[c * 2 + t2];
        acc = __builtin_amdgcn_mfma_f32_16x16x32_bf16(qh[ks], kf, acc, 0, 0, 0);
        acc = __builtin_amdgcn_mfma_f32_16x16x32_bf16(ql[ks], kf, acc, 0, 0, 0);
        S[c * 2 + t2] = acc;
      }
    }
  }

  // ---- softmax: row r lives on C-reg index; reduce across the 16-lane group ----
  float mx[4] = {-3e38f, -3e38f, -3e38f, -3e38f};
#pragma unroll
  for (int t = 0; t < 10; ++t) {
    int col = t * 16 + l15;
    bool valid = (col >= W_ - A);   // ctx: A-W+col >= 0 ; draft cols >=128 always valid
#pragma unroll
    for (int r = 0; r < 4; ++r) {
      float v = S[t][r] * SCALE_;
      v = valid ? v : -1e30f;
      S[t][r] = v;
      mx[r] = fmaxf(mx[r], v);
    }
  }
#pragma unroll
  for (int r = 0; r < 4; ++r)
#pragma unroll
    for (int mk = 1; mk < 16; mk <<= 1)
      mx[r] = fmaxf(mx[r], __shfl_xor(mx[r], mk));

  float ls[4] = {0.f, 0.f, 0.f, 0.f};
#pragma unroll
  for (int t = 0; t < 10; ++t) {
#pragma unroll
    for (int r = 0; r < 4; ++r) {
      float p = exp2f((S[t][r] - mx[r]) * L2E_);
      S[t][r] = p;
      ls[r] += p;
    }
  }
#pragma unroll
  for (int r = 0; r < 4; ++r)
#pragma unroll
    for (int mk = 1; mk < 16; mk <<= 1)
      ls[r] += __shfl_xor(ls[r], mk);

  // write unnormalized P (bf16) to pb[32][168]; each wave writes/reads only its own rows
#pragma unroll
  for (int t = 0; t < 10; ++t) {
#pragma unroll
    for (int r = 0; r < 4; ++r) {
      pb[(wu * 16 + g * 4 + r) * 168 + t * 16 + l15] = bfrne(S[t][r]);
    }
  }

  // ---- Phase 2: O = P V (chunks of 32 keys, V staged transposed) ----
  fx4 oacc[8];
#pragma unroll
  for (int t = 0; t < 8; ++t) oacc[t] = {0.f, 0.f, 0.f, 0.f};

#pragma unroll
  for (int c = 0; c < 5; ++c) {
    __syncthreads();   // previous chunk consumed (also covers P writes on c==0)
#pragma unroll
    for (int pass = 0; pass < 2; ++pass) {
      int keyl = pass * 16 + rb * 4;
      f4 rr[4];
#pragma unroll
      for (int i = 0; i < 4; ++i) {
        int key = c * 32 + keyl + i;
        const float* src;
        if (key < W_) {
          int idx = A - W_ + key; idx = idx < 0 ? 0 : idx;
          src = v_ctx + ((size_t)h * T_ + idx) * D_;
        } else {
          src = v_draft + ((size_t)h * NQ_ + (size_t)n * BS_ + (key - W_)) * D_;
        }
        rr[i] = reinterpret_cast<const f4*>(src)[c4];
      }
#pragma unroll
      for (int j = 0; j < 4; ++j) {   // 4x4 in-register transpose -> vT[d][key]
        s4 w = { bfrne(rr[0][j]), bfrne(rr[1][j]), bfrne(rr[2][j]), bfrne(rr[3][j]) };
        *reinterpret_cast<s4*>(vT + (c4 * 4 + j) * 36 + keyl) = w;
      }
    }
    __syncthreads();
    // A-frag = P rows (this wave's own queries)
    const short* pp = pb + (wu * 16 + l15) * 168 + c * 32 + g * 4;
    s4 a0 = *reinterpret_cast<const s4*>(pp);
    s4 a1 = *reinterpret_cast<const s4*>(pp + 16);
    s8 pa = { a0[0], a0[1], a0[2], a0[3], a1[0], a1[1], a1[2], a1[3] };
#pragma unroll
    for (int nt = 0; nt < 8; ++nt) {
      const short* vp = vT + (nt * 16 + l15) * 36 + g * 4;
      s4 b0 = *reinterpret_cast<const s4*>(vp);
      s4 b1 = *reinterpret_cast<const s4*>(vp + 16);
      s8 vb = { b0[0], b0[1], b0[2], b0[3], b1[0], b1[1], b1[2], b1[3] };
      oacc[nt] = __builtin_amdgcn_mfma_f32_16x16x32_bf16(pa, vb, oacc[nt], 0, 0, 0);
    }
  }

  // ---- epilogue: normalize, apply keep, store ----
  float* orow = out + ((size_t)h * NQ_ + (size_t)n * BS_ + wu * 16 + g * 4) * D_;
#pragma unroll
  for (int nt = 0; nt < 8; ++nt) {
#pragma unroll
    for (int r = 0; r < 4; ++r) {
      float o = kp ? (oacc[nt][r] / ls[r]) : 0.0f;
      orow[(size_t)r * D_ + nt * 16 + l15] = o;
    }
  }
}

extern "C" void kernel_launch(void* const* d_in, const int* in_sizes, int n_in,
                              void* d_out, int out_size, void* d_ws, size_t ws_size,
                              hipStream_t stream) {
  (void)in_sizes; (void)n_in; (void)d_ws; (void)ws_size; (void)out_size;
  const float* q       = (const float*)d_in[0];
  const float* k_ctx   = (const float*)d_in[1];
  const float* v_ctx   = (const float*)d_in[2];
  const float* k_draft = (const float*)d_in[3];
  const float* v_draft = (const float*)d_in[4];
  const int*   anchor  = (const int*)d_in[5];
  const int*   keep    = (const int*)d_in[6];
  float*       out     = (float*)d_out;
  mtp_attn_kernel<<<dim3(8192), dim3(128), 0, stream>>>(
      q, k_ctx, v_ctx, k_draft, v_draft, anchor, keep, out);
}